// Round 1
// 1269.314 us; speedup vs baseline: 1.4291x; 1.4291x over previous
//
#include <hip/hip_runtime.h>
#include <cstdint>
#include <cstddef>

// Problem: GatedGCN layer. N=50000 nodes, E=640000 edges, D=128. fp32 in/out.
// ws layout (floats): NodeFeat [N*512] | aggr [N*128] | h [N*256]
// Ce is staged in d_out's e_final region (E*128 floats) before edge_apply
// overwrites it in place with the final e output.

__device__ __forceinline__ float4 ld4(const float* p) { return *reinterpret_cast<const float4*>(p); }

// ---------------------------------------------------------------------------
// 128x128-tile fp32 GEMM, 256 threads, 8x8 per-thread micro-tile split as
// 4+4 rows x 4+4 cols (64-apart halves) so LDS fragment reads are at float4
// stride -> <=2-way bank aliasing (free). A staged transposed in LDS so the
// k-loop A reads are b128. KC=32 chunks keep LDS at ~33 KB (4 blocks/CU).
// ---------------------------------------------------------------------------
template<bool RELU, bool RES>
__device__ __forceinline__ void gemm128(
    const float* __restrict__ A, int lda, int M, int K, int row0,
    const float* __restrict__ B, int ldb,          // col-section view, 128 cols used
    const float* __restrict__ bias,                // col-section view, 128 entries
    const float* __restrict__ res, int ldr,        // col-section view (if RES)
    float* __restrict__ C, int ldc)                // col-section view
{
    __shared__ float AsT[32][132];                 // [k][row], pad keeps rows 16B-aligned
    __shared__ float Bs[32][128];                  // [k][col]
    const int t  = threadIdx.x;
    const int tx = t & 15, ty = t >> 4;
    float acc[8][8] = {};

    for (int kk = 0; kk < K; kk += 32) {
        #pragma unroll
        for (int i = 0; i < 4; ++i) {              // stage A chunk: 128 rows x 32 k
            int idx = t + i * 256;                 // 1024 float4 slots
            int r = idx >> 3, c4 = idx & 7;
            int gr = row0 + r;
            float4 v = make_float4(0.f, 0.f, 0.f, 0.f);
            if (gr < M) v = ld4(A + (size_t)gr * lda + kk + c4 * 4);
            AsT[c4 * 4 + 0][r] = v.x;              // transposed store
            AsT[c4 * 4 + 1][r] = v.y;
            AsT[c4 * 4 + 2][r] = v.z;
            AsT[c4 * 4 + 3][r] = v.w;
        }
        #pragma unroll
        for (int i = 0; i < 4; ++i) {              // stage B chunk: 32 k x 128 cols
            int idx = t + i * 256;
            int k = idx >> 5, c4 = idx & 31;
            *reinterpret_cast<float4*>(&Bs[k][c4 * 4]) =
                ld4(B + (size_t)(kk + k) * ldb + c4 * 4);
        }
        __syncthreads();
        #pragma unroll
        for (int k = 0; k < 32; ++k) {
            float4 a0 = *reinterpret_cast<const float4*>(&AsT[k][ty * 4]);
            float4 a1 = *reinterpret_cast<const float4*>(&AsT[k][64 + ty * 4]);
            float4 b0 = *reinterpret_cast<const float4*>(&Bs[k][tx * 4]);
            float4 b1 = *reinterpret_cast<const float4*>(&Bs[k][64 + tx * 4]);
            float a[8] = {a0.x, a0.y, a0.z, a0.w, a1.x, a1.y, a1.z, a1.w};
            float b[8] = {b0.x, b0.y, b0.z, b0.w, b1.x, b1.y, b1.z, b1.w};
            #pragma unroll
            for (int i = 0; i < 8; ++i)
                #pragma unroll
                for (int j = 0; j < 8; ++j)
                    acc[i][j] = fmaf(a[i], b[j], acc[i][j]);
        }
        __syncthreads();
    }

    #pragma unroll
    for (int hi = 0; hi < 2; ++hi) {
        #pragma unroll
        for (int i = 0; i < 4; ++i) {
            int gr = row0 + hi * 64 + ty * 4 + i;
            if (gr >= M) continue;
            #pragma unroll
            for (int hj = 0; hj < 2; ++hj) {
                int c = hj * 64 + tx * 4;
                float4 v;
                v.x = acc[hi * 4 + i][hj * 4 + 0] + bias[c + 0];
                v.y = acc[hi * 4 + i][hj * 4 + 1] + bias[c + 1];
                v.z = acc[hi * 4 + i][hj * 4 + 2] + bias[c + 2];
                v.w = acc[hi * 4 + i][hj * 4 + 3] + bias[c + 3];
                if (RELU) {
                    v.x = fmaxf(v.x, 0.f); v.y = fmaxf(v.y, 0.f);
                    v.z = fmaxf(v.z, 0.f); v.w = fmaxf(v.w, 0.f);
                }
                if (RES) {
                    float4 rv = ld4(res + (size_t)gr * ldr + c);
                    v.x += rv.x; v.y += rv.y; v.z += rv.z; v.w += rv.w;
                }
                *reinterpret_cast<float4*>(&C[(size_t)gr * ldc + c]) = v;
            }
        }
    }
}

// NodeFeat[N][512] = x @ [WA|WB|WD|WE] + [bA|bB|bD|bE]
__global__ __launch_bounds__(256, 3) void node_gemm4_kernel(
    const float* __restrict__ x,
    const float* __restrict__ WA, const float* __restrict__ bA,
    const float* __restrict__ WB, const float* __restrict__ bB,
    const float* __restrict__ WD, const float* __restrict__ bD,
    const float* __restrict__ WE, const float* __restrict__ bE,
    float* __restrict__ NodeFeat, int N)
{
    int sec = blockIdx.y;
    const float* W = sec == 0 ? WA : sec == 1 ? WB : sec == 2 ? WD : WE;
    const float* b = sec == 0 ? bA : sec == 1 ? bB : sec == 2 ? bD : bE;
    gemm128<false, false>(x, 128, N, 128, blockIdx.x * 128, W, 128, b,
                          nullptr, 0, NodeFeat + (size_t)sec * 128, 512);
}

// Ce+bC for all edges -> staged into d_out's e_final region (scratch)
__global__ __launch_bounds__(256, 3) void ce_kernel(
    const float* __restrict__ edge_attr, const float* __restrict__ WC,
    const float* __restrict__ bC, float* __restrict__ ce_out, int E)
{
    gemm128<false, false>(edge_attr, 128, E, 128, blockIdx.x * 128, WC, 128, bC,
                          nullptr, 0, ce_out, 128);
}

__global__ __launch_bounds__(256, 3) void ffn1_kernel(
    const float* __restrict__ xfp, const float* __restrict__ W1,
    const float* __restrict__ b1, float* __restrict__ h, int N)
{
    int cb = blockIdx.y * 128;
    gemm128<true, false>(xfp, 128, N, 128, blockIdx.x * 128, W1 + cb, 256, b1 + cb,
                         nullptr, 0, h + cb, 256);
}

__global__ __launch_bounds__(256, 3) void ffn2_kernel(
    const float* __restrict__ h, const float* __restrict__ W2,
    const float* __restrict__ b2, const float* __restrict__ xfp,
    float* __restrict__ xout, int N)
{
    gemm128<false, true>(h, 256, N, 256, blockIdx.x * 128, W2, 128, b2,
                         xfp, 128, xout, 128);
}

// ---------------------------------------------------------------------------
// Streaming edge epilogue: zero LDS, low VGPR -> high occupancy to hide the
// NodeFeat gather latency. Reads Ce (in e_final region), overwrites in place.
// 8 edges per block; each thread owns 4 independent (edge,feature) tasks.
// ---------------------------------------------------------------------------
__global__ __launch_bounds__(256) void edge_apply(
    const float* __restrict__ edge_attr, const float* __restrict__ edge_w,
    const int* __restrict__ rowI, const int* __restrict__ colI,
    const float* __restrict__ NodeFeat,      // [N][512] = Ax|Bx|Dx|Ex
    float* __restrict__ e_final,             // in: Ce+bC, out: final e
    float* __restrict__ aggr, int E)
{
    const int t  = threadIdx.x;
    const int f  = t & 127;
    const int e0 = blockIdx.x * 8 + (t >> 7);
    #pragma unroll
    for (int i = 0; i < 4; ++i) {
        int e = e0 + i * 2;
        if (e >= E) continue;
        int   r  = rowI[e], c = colI[e];
        float w  = edge_w[e];
        float ce = e_final[(size_t)e * 128 + f];
        float ea = edge_attr[(size_t)e * 128 + f];
        float dx = NodeFeat[(size_t)r * 512 + 256 + f];   // Dx[row]
        float ex = NodeFeat[(size_t)c * 512 + 384 + f];   // Ex[col]
        float bx = NodeFeat[(size_t)c * 512 + 128 + f];   // Bx[col]
        float eij = ce + dx + ex;
        float sg  = 1.f / (1.f + __expf(-eij));
        e_final[(size_t)e * 128 + f] = ea + fmaxf(eij, 0.f);
        atomicAdd(&aggr[(size_t)r * 128 + f], w * sg * bx);
    }
}

// xfp = x + relu(Ax + aggr)   (written straight into d_out's x region)
__global__ __launch_bounds__(256) void node_combine(
    const float* __restrict__ x, const float* __restrict__ NodeFeat,
    const float* __restrict__ aggr, float* __restrict__ xfp, int N)
{
    int i4 = blockIdx.x * blockDim.x + threadIdx.x;   // over N*32 float4s
    if (i4 >= N * 32) return;
    int row = i4 >> 5, c4 = i4 & 31;
    float4 xa = ld4(x + (size_t)i4 * 4);
    float4 ax = ld4(NodeFeat + (size_t)row * 512 + c4 * 4);
    float4 ag = ld4(aggr + (size_t)i4 * 4);
    float4 o;
    o.x = xa.x + fmaxf(ax.x + ag.x, 0.f);
    o.y = xa.y + fmaxf(ax.y + ag.y, 0.f);
    o.z = xa.z + fmaxf(ax.z + ag.z, 0.f);
    o.w = xa.w + fmaxf(ax.w + ag.w, 0.f);
    *reinterpret_cast<float4*>(xfp + (size_t)i4 * 4) = o;
}

extern "C" void kernel_launch(void* const* d_in, const int* in_sizes, int n_in,
                              void* d_out, int out_size, void* d_ws, size_t ws_size,
                              hipStream_t stream)
{
    const float* x         = (const float*)d_in[0];
    const float* edge_attr = (const float*)d_in[1];
    const float* edge_w    = (const float*)d_in[2];
    const float* WA = (const float*)d_in[3];  const float* bA = (const float*)d_in[4];
    const float* WB = (const float*)d_in[5];  const float* bB = (const float*)d_in[6];
    const float* WC = (const float*)d_in[7];  const float* bC = (const float*)d_in[8];
    const float* WD = (const float*)d_in[9];  const float* bD = (const float*)d_in[10];
    const float* WE = (const float*)d_in[11]; const float* bE = (const float*)d_in[12];
    const float* W1 = (const float*)d_in[13]; const float* b1 = (const float*)d_in[14];
    const float* W2 = (const float*)d_in[15]; const float* b2 = (const float*)d_in[16];
    const int*   eidx = (const int*)d_in[17];

    const int N = in_sizes[0] / 128;
    const int E = in_sizes[2];
    const int* rowI = eidx;
    const int* colI = eidx + E;

    float* ws       = (float*)d_ws;
    float* NodeFeat = ws;                         // N*512
    float* aggr     = ws + (size_t)N * 512;       // N*128
    float* h        = ws + (size_t)N * 640;       // N*256
    float* xfp      = (float*)d_out;              // N*128  (x_final region)
    float* e_final  = (float*)d_out + (size_t)N * 128;   // E*128 (Ce scratch, then e out)

    const int rowTiles = (N + 127) / 128;

    hipMemsetAsync(aggr, 0, (size_t)N * 128 * sizeof(float), stream);
    node_gemm4_kernel<<<dim3(rowTiles, 4), 256, 0, stream>>>(
        x, WA, bA, WB, bB, WD, bD, WE, bE, NodeFeat, N);
    ce_kernel<<<dim3((E + 127) / 128), 256, 0, stream>>>(
        edge_attr, WC, bC, e_final, E);
    edge_apply<<<dim3((E + 7) / 8), 256, 0, stream>>>(
        edge_attr, edge_w, rowI, colI, NodeFeat, e_final, aggr, E);
    node_combine<<<dim3((N * 32 + 255) / 256), 256, 0, stream>>>(
        x, NodeFeat, aggr, xfp, N);
    ffn1_kernel<<<dim3(rowTiles, 2), 256, 0, stream>>>(xfp, W1, b1, h, N);
    ffn2_kernel<<<dim3(rowTiles, 1), 256, 0, stream>>>(h, W2, b2, xfp, xfp, N);
}

// Round 2
// 1086.630 us; speedup vs baseline: 1.6693x; 1.1681x over previous
//
#include <hip/hip_runtime.h>
#include <cstdint>
#include <cstddef>

// GatedGCN layer. N=50000 nodes, E=640000 edges, D=128. fp32 in/out.
// GEMMs run on MFMA via bf16x3 split (Ah*Bh + Ah*Bl + Al*Bh, fp32 accum):
// fp32-grade accuracy at matrix-core rate. Weights pre-converted once to
// transposed bf16 hi/lo panels [N][K] so B-fragments are single b128 loads.
//
// ws layout (floats): NodeFeat [N*512] | aggr [N*128] | h [N*256]
//   - h region head doubles as scratch for {WcatT,WCt,bcat} (dead until ffn1)
//   - NodeFeat region doubles as scratch for {W1t,W2t} (dead after node_combine)
// Ce is staged in d_out's e_final region before edge_apply overwrites it.

typedef __attribute__((ext_vector_type(8))) short short8;   // 8 bf16 (4 VGPRs)
typedef __attribute__((ext_vector_type(4))) float f32x4;    // MFMA C/D

__device__ __forceinline__ float4 ld4(const float* p) { return *reinterpret_cast<const float4*>(p); }

// pack fp32 -> (bf16_hi << 16) | bf16_lo, both RNE. lo = RNE(f - float(hi)).
__device__ __forceinline__ uint32_t pack_bf16x2(float f) {
    uint32_t u  = __float_as_uint(f);
    uint32_t hi = (u + 0x7fffu + ((u >> 16) & 1u)) >> 16;
    float    fh = __uint_as_float(hi << 16);
    uint32_t v  = __float_as_uint(f - fh);
    uint32_t lo = (v + 0x7fffu + ((v >> 16) & 1u)) >> 16;
    return (hi << 16) | (lo & 0xffffu);
}

// ---------------------------------------------------------------------------
// MFMA GEMM: block = 64 rows x (NW*64) cols, NW waves, each wave owns a
// 64x64 output tile = 4x4 fragments of 16x16, K-chunks of 32.
// A: fp32 global -> packed hi/lo uint32 in LDS (reg-double-buffered).
// B: pre-converted bf16 hi/lo, transposed [N][K] -> one b128 per fragment.
// Fragment maps (m89-verified): A row / B col / D col = lane&15;
// D row = (lane>>4)*4 + reg. k-map (lane>>4)*8+j identical for A and B,
// so any true k-permutation cancels in the dot product.
// ---------------------------------------------------------------------------
template<int NW, bool RELU, bool RES>
__device__ __forceinline__ void mfma_gemm(
    const float* __restrict__ A, int lda, int M, int K, int row0,
    const short* __restrict__ BhT, const short* __restrict__ BlT,  // [Nsec][K]
    const float* __restrict__ bias,                                // Nsec view
    const float* __restrict__ res, int ldr,                        // if RES
    float* __restrict__ C, int ldc)                                // Nsec view
{
    __shared__ uint32_t As[64][36];            // [row][k], pad 36 -> <=2-way banks
    constexpr int NT = NW * 64;
    constexpr int IT = 512 / NT;               // float4 slots per thread (64x32/4)
    const int t    = threadIdx.x;
    const int lane = t & 63;
    const int l15  = lane & 15, kg = lane >> 4;
    const int wsec = (t >> 6) * 64;            // this wave's col base

    f32x4 acc[4][4] = {};
    float bv[4];
    #pragma unroll
    for (int fn = 0; fn < 4; ++fn) bv[fn] = bias[wsec + fn * 16 + l15];

    float4 vbuf[IT];
    #pragma unroll
    for (int i = 0; i < IT; ++i) {             // prologue: load chunk 0
        int idx = t + i * NT, r = idx >> 3, c4 = idx & 7;
        int gr = row0 + r;
        vbuf[i] = (gr < M) ? ld4(A + (size_t)gr * lda + c4 * 4)
                           : make_float4(0.f, 0.f, 0.f, 0.f);
    }

    for (int kk = 0; kk < K; kk += 32) {
        #pragma unroll
        for (int i = 0; i < IT; ++i) {         // convert + stage to LDS
            int idx = t + i * NT, r = idx >> 3, c4 = idx & 7;
            uint4 p;
            p.x = pack_bf16x2(vbuf[i].x); p.y = pack_bf16x2(vbuf[i].y);
            p.z = pack_bf16x2(vbuf[i].z); p.w = pack_bf16x2(vbuf[i].w);
            *reinterpret_cast<uint4*>(&As[r][c4 * 4]) = p;
        }
        __syncthreads();

        if (kk + 32 < K) {                     // issue next-chunk loads early:
            #pragma unroll                     // HBM latency hides under MFMA
            for (int i = 0; i < IT; ++i) {
                int idx = t + i * NT, r = idx >> 3, c4 = idx & 7;
                int gr = row0 + r;
                vbuf[i] = (gr < M) ? ld4(A + (size_t)gr * lda + kk + 32 + c4 * 4)
                                   : make_float4(0.f, 0.f, 0.f, 0.f);
            }
        }

        short8 bh[4], bl[4];
        #pragma unroll
        for (int fn = 0; fn < 4; ++fn) {       // B fragments: b128 L2 hits
            const size_t bo = (size_t)(wsec + fn * 16 + l15) * K + kk + kg * 8;
            bh[fn] = *reinterpret_cast<const short8*>(BhT + bo);
            bl[fn] = *reinterpret_cast<const short8*>(BlT + bo);
        }

        #pragma unroll
        for (int fm = 0; fm < 4; ++fm) {
            uint4 a0 = *reinterpret_cast<const uint4*>(&As[fm * 16 + l15][kg * 8]);
            uint4 a1 = *reinterpret_cast<const uint4*>(&As[fm * 16 + l15][kg * 8 + 4]);
            short8 ah, al;
            ah[0] = (short)(a0.x >> 16); al[0] = (short)a0.x;
            ah[1] = (short)(a0.y >> 16); al[1] = (short)a0.y;
            ah[2] = (short)(a0.z >> 16); al[2] = (short)a0.z;
            ah[3] = (short)(a0.w >> 16); al[3] = (short)a0.w;
            ah[4] = (short)(a1.x >> 16); al[4] = (short)a1.x;
            ah[5] = (short)(a1.y >> 16); al[5] = (short)a1.y;
            ah[6] = (short)(a1.z >> 16); al[6] = (short)a1.z;
            ah[7] = (short)(a1.w >> 16); al[7] = (short)a1.w;
            #pragma unroll
            for (int fn = 0; fn < 4; ++fn) {
                acc[fm][fn] = __builtin_amdgcn_mfma_f32_16x16x32_bf16(ah, bh[fn], acc[fm][fn], 0, 0, 0);
                acc[fm][fn] = __builtin_amdgcn_mfma_f32_16x16x32_bf16(ah, bl[fn], acc[fm][fn], 0, 0, 0);
                acc[fm][fn] = __builtin_amdgcn_mfma_f32_16x16x32_bf16(al, bh[fn], acc[fm][fn], 0, 0, 0);
            }
        }
        __syncthreads();
    }

    #pragma unroll
    for (int fm = 0; fm < 4; ++fm) {
        #pragma unroll
        for (int i = 0; i < 4; ++i) {
            int gr = row0 + fm * 16 + kg * 4 + i;
            if (gr >= M) continue;
            #pragma unroll
            for (int fn = 0; fn < 4; ++fn) {
                int col = wsec + fn * 16 + l15;
                float v = acc[fm][fn][i] + bv[fn];
                if (RELU) v = fmaxf(v, 0.f);
                if (RES)  v += res[(size_t)gr * ldr + col];
                C[(size_t)gr * ldc + col] = v;
            }
        }
    }
}

// ---- weight pre-conversion -------------------------------------------------
// convert1: WA|WB|WD|WE -> WcatT[512][128] hi/lo, WC -> WCt[128][128] hi/lo,
//           bcat[512]. Into h-region scratch (dead until ffn1).
__global__ __launch_bounds__(256) void convert1(
    const float* __restrict__ WA, const float* __restrict__ WB,
    const float* __restrict__ WD, const float* __restrict__ WE,
    const float* __restrict__ WC,
    const float* __restrict__ bA, const float* __restrict__ bB,
    const float* __restrict__ bD, const float* __restrict__ bE,
    short* __restrict__ WcatT_h, short* __restrict__ WcatT_l,
    short* __restrict__ WCt_h, short* __restrict__ WCt_l,
    float* __restrict__ bcat)
{
    int tid = blockIdx.x * 256 + threadIdx.x;
    if (tid < 65536) {
        int k = tid & 127, n = tid >> 7;
        int sec = n >> 7, nn = n & 127;
        const float* W = sec == 0 ? WA : sec == 1 ? WB : sec == 2 ? WD : WE;
        uint32_t p = pack_bf16x2(W[k * 128 + nn]);
        WcatT_h[n * 128 + k] = (short)(p >> 16);
        WcatT_l[n * 128 + k] = (short)p;
    } else if (tid < 81920) {
        int idx = tid - 65536, k = idx & 127, n = idx >> 7;
        uint32_t p = pack_bf16x2(WC[k * 128 + n]);
        WCt_h[n * 128 + k] = (short)(p >> 16);
        WCt_l[n * 128 + k] = (short)p;
    } else if (tid < 82432) {
        int c = tid - 81920, sec = c >> 7;
        const float* b = sec == 0 ? bA : sec == 1 ? bB : sec == 2 ? bD : bE;
        bcat[c] = b[c & 127];
    }
}

// convert2: W1[128][256] -> W1t[256][128] hi/lo; W2[256][128] -> W2t[128][256]
// hi/lo. Into NodeFeat-region scratch (dead after node_combine).
__global__ __launch_bounds__(256) void convert2(
    const float* __restrict__ W1, const float* __restrict__ W2,
    short* __restrict__ W1t_h, short* __restrict__ W1t_l,
    short* __restrict__ W2t_h, short* __restrict__ W2t_l)
{
    int tid = blockIdx.x * 256 + threadIdx.x;
    if (tid < 32768) {
        int k = tid & 127, n = tid >> 7;
        uint32_t p = pack_bf16x2(W1[k * 256 + n]);
        W1t_h[n * 128 + k] = (short)(p >> 16);
        W1t_l[n * 128 + k] = (short)p;
    } else if (tid < 65536) {
        int idx = tid - 32768, k = idx & 255, n = idx >> 8;
        uint32_t p = pack_bf16x2(W2[k * 128 + n]);
        W2t_h[n * 256 + k] = (short)(p >> 16);
        W2t_l[n * 256 + k] = (short)p;
    }
}

// ---- GEMM wrappers ---------------------------------------------------------
__global__ __launch_bounds__(256) void node_gemm4_mfma(
    const float* __restrict__ x, const short* __restrict__ WcatT_h,
    const short* __restrict__ WcatT_l, const float* __restrict__ bcat,
    float* __restrict__ NodeFeat, int N)
{
    int col0 = blockIdx.y * 256;
    mfma_gemm<4, false, false>(x, 128, N, 128, blockIdx.x * 64,
                               WcatT_h + (size_t)col0 * 128, WcatT_l + (size_t)col0 * 128,
                               bcat + col0, nullptr, 0, NodeFeat + col0, 512);
}

__global__ __launch_bounds__(128) void ce_mfma(
    const float* __restrict__ edge_attr, const short* __restrict__ WCt_h,
    const short* __restrict__ WCt_l, const float* __restrict__ bC,
    float* __restrict__ ce_out, int E)
{
    mfma_gemm<2, false, false>(edge_attr, 128, E, 128, blockIdx.x * 64,
                               WCt_h, WCt_l, bC, nullptr, 0, ce_out, 128);
}

__global__ __launch_bounds__(256) void ffn1_mfma(
    const float* __restrict__ xfp, const short* __restrict__ W1t_h,
    const short* __restrict__ W1t_l, const float* __restrict__ b1,
    float* __restrict__ h, int N)
{
    mfma_gemm<4, true, false>(xfp, 128, N, 128, blockIdx.x * 64,
                              W1t_h, W1t_l, b1, nullptr, 0, h, 256);
}

__global__ __launch_bounds__(128) void ffn2_mfma(
    const float* __restrict__ h, const short* __restrict__ W2t_h,
    const short* __restrict__ W2t_l, const float* __restrict__ b2,
    const float* __restrict__ xfp, float* __restrict__ xout, int N)
{
    mfma_gemm<2, false, true>(h, 256, N, 256, blockIdx.x * 64,
                              W2t_h, W2t_l, b2, xfp, 128, xout, 128);
}

// ---------------------------------------------------------------------------
// Streaming edge epilogue (unchanged): zero LDS, 12 VGPR, ~90% occupancy.
// ---------------------------------------------------------------------------
__global__ __launch_bounds__(256) void edge_apply(
    const float* __restrict__ edge_attr, const float* __restrict__ edge_w,
    const int* __restrict__ rowI, const int* __restrict__ colI,
    const float* __restrict__ NodeFeat,      // [N][512] = Ax|Bx|Dx|Ex
    float* __restrict__ e_final,             // in: Ce+bC, out: final e
    float* __restrict__ aggr, int E)
{
    const int t  = threadIdx.x;
    const int f  = t & 127;
    const int e0 = blockIdx.x * 8 + (t >> 7);
    #pragma unroll
    for (int i = 0; i < 4; ++i) {
        int e = e0 + i * 2;
        if (e >= E) continue;
        int   r  = rowI[e], c = colI[e];
        float w  = edge_w[e];
        float ce = e_final[(size_t)e * 128 + f];
        float ea = edge_attr[(size_t)e * 128 + f];
        float dx = NodeFeat[(size_t)r * 512 + 256 + f];
        float ex = NodeFeat[(size_t)c * 512 + 384 + f];
        float bx = NodeFeat[(size_t)c * 512 + 128 + f];
        float eij = ce + dx + ex;
        float sg  = 1.f / (1.f + __expf(-eij));
        e_final[(size_t)e * 128 + f] = ea + fmaxf(eij, 0.f);
        atomicAdd(&aggr[(size_t)r * 128 + f], w * sg * bx);
    }
}

// xfp = x + relu(Ax + aggr)
__global__ __launch_bounds__(256) void node_combine(
    const float* __restrict__ x, const float* __restrict__ NodeFeat,
    const float* __restrict__ aggr, float* __restrict__ xfp, int N)
{
    int i4 = blockIdx.x * blockDim.x + threadIdx.x;
    if (i4 >= N * 32) return;
    int row = i4 >> 5, c4 = i4 & 31;
    float4 xa = ld4(x + (size_t)i4 * 4);
    float4 ax = ld4(NodeFeat + (size_t)row * 512 + c4 * 4);
    float4 ag = ld4(aggr + (size_t)i4 * 4);
    float4 o;
    o.x = xa.x + fmaxf(ax.x + ag.x, 0.f);
    o.y = xa.y + fmaxf(ax.y + ag.y, 0.f);
    o.z = xa.z + fmaxf(ax.z + ag.z, 0.f);
    o.w = xa.w + fmaxf(ax.w + ag.w, 0.f);
    *reinterpret_cast<float4*>(xfp + (size_t)i4 * 4) = o;
}

extern "C" void kernel_launch(void* const* d_in, const int* in_sizes, int n_in,
                              void* d_out, int out_size, void* d_ws, size_t ws_size,
                              hipStream_t stream)
{
    const float* x         = (const float*)d_in[0];
    const float* edge_attr = (const float*)d_in[1];
    const float* edge_w    = (const float*)d_in[2];
    const float* WA = (const float*)d_in[3];  const float* bA = (const float*)d_in[4];
    const float* WB = (const float*)d_in[5];  const float* bB = (const float*)d_in[6];
    const float* WC = (const float*)d_in[7];  const float* bC = (const float*)d_in[8];
    const float* WD = (const float*)d_in[9];  const float* bD = (const float*)d_in[10];
    const float* WE = (const float*)d_in[11]; const float* bE = (const float*)d_in[12];
    const float* W1 = (const float*)d_in[13]; const float* b1 = (const float*)d_in[14];
    const float* W2 = (const float*)d_in[15]; const float* b2 = (const float*)d_in[16];
    const int*   eidx = (const int*)d_in[17];

    const int N = in_sizes[0] / 128;
    const int E = in_sizes[2];
    const int* rowI = eidx;
    const int* colI = eidx + E;

    float* ws       = (float*)d_ws;
    float* NodeFeat = ws;                         // N*512
    float* aggr     = ws + (size_t)N * 512;       // N*128
    float* h        = ws + (size_t)N * 640;       // N*256
    float* xfp      = (float*)d_out;              // N*128
    float* e_final  = (float*)d_out + (size_t)N * 128;   // E*128 (Ce scratch)

    // scratch carve-outs
    short* cs      = (short*)h;                   // h region: dead until ffn1
    short* WcatT_h = cs;                          // 512*128
    short* WcatT_l = cs + 65536;
    short* WCt_h   = cs + 131072;                 // 128*128
    short* WCt_l   = cs + 147456;
    float* bcat    = h + 81920;                   // 512 floats
    short* cs2     = (short*)NodeFeat;            // dead after node_combine
    short* W1t_h   = cs2;                         // 256*128
    short* W1t_l   = cs2 + 32768;
    short* W2t_h   = cs2 + 65536;                 // 128*256
    short* W2t_l   = cs2 + 98304;

    const int rowTiles = (N + 63) / 64;           // 782
    const int ceTiles  = (E + 63) / 64;           // 10000

    convert1<<<dim3(322), 256, 0, stream>>>(WA, WB, WD, WE, WC, bA, bB, bD, bE,
                                            WcatT_h, WcatT_l, WCt_h, WCt_l, bcat);
    hipMemsetAsync(aggr, 0, (size_t)N * 128 * sizeof(float), stream);
    node_gemm4_mfma<<<dim3(rowTiles, 2), 256, 0, stream>>>(
        x, WcatT_h, WcatT_l, bcat, NodeFeat, N);
    ce_mfma<<<dim3(ceTiles), 128, 0, stream>>>(
        edge_attr, WCt_h, WCt_l, bC, e_final, E);
    edge_apply<<<dim3((E + 7) / 8), 256, 0, stream>>>(
        edge_attr, edge_w, rowI, colI, NodeFeat, e_final, aggr, E);
    node_combine<<<dim3((N * 32 + 255) / 256), 256, 0, stream>>>(
        x, NodeFeat, aggr, xfp, N);
    convert2<<<dim3(256), 256, 0, stream>>>(W1, W2, W1t_h, W1t_l, W2t_h, W2t_l);
    ffn1_mfma<<<dim3(rowTiles), 256, 0, stream>>>(xfp, W1t_h, W1t_l, b1, h, N);
    ffn2_mfma<<<dim3(rowTiles), 128, 0, stream>>>(h, W2t_h, W2t_l, b2, xfp, xfp, N);
}